// Round 7
// baseline (167.680 us; speedup 1.0000x reference)
//
#include <hip/hip_runtime.h>

// Roformer MHA: T=2048 B=2 E=1024 H=16 HD=64
#define T_  2048
#define B_  2
#define E_  1024
#define H_  16
#define HD_ 64
#define M_  4096          // T*B rows
#define N_QKV 3072        // 3*E

typedef unsigned short u16;
typedef unsigned int   u32;
typedef __attribute__((ext_vector_type(8))) __bf16 bf16x8;
typedef __attribute__((ext_vector_type(4))) float  f32x4;

__device__ inline u16 f2bf(float f) {
  u32 u = __float_as_uint(f);
  u += 0x7fffu + ((u >> 16) & 1u);   // RTNE (finite values)
  return (u16)(u >> 16);
}

__device__ inline void gl_lds16(const u16* g, u16* l) {
  __builtin_amdgcn_global_load_lds(
      (const __attribute__((address_space(1))) u32*)g,
      (__attribute__((address_space(3))) u32*)l, 16, 0, 0);
}

// T1: bijective XCD-aware block swizzle (requires nwg % 8 == 0)
__device__ inline int xcd_swz(int orig, int nwg) {
  return (orig & 7) * (nwg >> 3) + (orig >> 3);
}

// ---------------- Pass A: fp32 -> bf16 conversion --------------------------
__global__ __launch_bounds__(256) void cvt_kernel(
    const float* __restrict__ q, const float* __restrict__ wi,
    const float* __restrict__ wo, u16* __restrict__ X,
    u16* __restrict__ Wi, u16* __restrict__ Wo) {
  int idx = blockIdx.x * 256 + threadIdx.x;       // one float4 per thread
  const int n1 = (M_ * E_) / 4, n2 = (3 * E_ * E_) / 4;
  const float4* src; u16* dst; int i;
  if (idx < n1)            { src = (const float4*)q;  dst = X;  i = idx; }
  else if (idx < n1 + n2)  { src = (const float4*)wi; dst = Wi; i = idx - n1; }
  else                     { src = (const float4*)wo; dst = Wo; i = idx - n1 - n2; }
  float4 v = src[i];
  uint2 o;
  o.x = (u32)f2bf(v.x) | ((u32)f2bf(v.y) << 16);
  o.y = (u32)f2bf(v.z) | ((u32)f2bf(v.w) << 16);
  *(uint2*)&dst[(size_t)i * 4] = o;
}

// ---------------- Pass B: QKV GEMM, 256x256 8-phase (T1+T2+T3+T4+T5) -------
// C[m][n] = sum_e X[m][e] * W[n][e],  M=4096, N=3072, K=1024, BK=64.
// 8 waves (2M x 4N); wave output = two 64-row pieces (one per A-half) x
// two 32-col pieces (one per B-half). Phases per K-tile: (0,0)(0,1)(1,1)(1,0).
// Stage order per tile t (into buf t+1): ph1:A0 ph2:B0 ph3:B1 ph4:A1.
// Counted vmcnt(4) at ends of ph1/ph2/ph4 (3 half-tiles in flight).
// Granule swizzle c ^= row&7 (linear gl_lds dest, swizzled source+read).
#define MMA16(MH, NH, BQ)                                              \
  __builtin_amdgcn_s_setprio(1);                                       \
  _Pragma("unroll")                                                    \
  for (int ks = 0; ks < 2; ++ks) {                                     \
    _Pragma("unroll")                                                  \
    for (int mi = 0; mi < 4; ++mi) {                                   \
      _Pragma("unroll")                                                \
      for (int ni = 0; ni < 2; ++ni)                                   \
        acc[MH][mi][NH][ni] = __builtin_amdgcn_mfma_f32_16x16x32_bf16( \
            af[mi][ks], BQ[ni][ks], acc[MH][mi][NH][ni], 0, 0, 0);     \
    }                                                                  \
  }                                                                    \
  __builtin_amdgcn_s_setprio(0);

#define PH_SYNC()                                        \
  __builtin_amdgcn_s_barrier();                          \
  asm volatile("s_waitcnt lgkmcnt(0)" ::: "memory");     \
  __builtin_amdgcn_sched_barrier(0);

__global__ __launch_bounds__(512, 2) void gemm_qkv(
    const u16* __restrict__ X, const u16* __restrict__ W,
    const float* __restrict__ bias, const float* __restrict__ rel,
    u16* __restrict__ qb, u16* __restrict__ kp, u16* __restrict__ vp) {
  const int K = E_;
  __shared__ u16 As[2][2][8192];     // [buf][half][128 rows * 64 cols]
  __shared__ u16 Bs[2][2][8192];
  int wgid = xcd_swz(blockIdx.x, 192);
  const int tm = (wgid & 15) * 256, tn = (wgid >> 4) * 256;
  const int tid = threadIdx.x;
  const int lane = tid & 63, w = tid >> 6, lr = lane & 15, lg = lane >> 4;
  const int wm = (w >> 2) * 64, wn = (w & 3) * 32;
  // staging: thread -> linear granules g0,g1; source column inverse-swizzled
  const int g0 = tid, g1 = tid + 512;
  const int r0 = g0 >> 3, c0 = (((g0 & 7) ^ (r0 & 7))) * 8;
  const int r1 = g1 >> 3, c1 = (((g1 & 7) ^ (r1 & 7))) * 8;

  f32x4 acc[2][4][2][2] = {};
  bf16x8 af[4][2], bq0[2][2], bq1[2][2];

  auto stA = [&](int buf, int h, int k0) {
    const u16* src = X + (size_t)(tm + h * 128) * K + k0;
    gl_lds16(src + (size_t)r0 * K + c0, &As[buf][h][g0 * 8]);
    gl_lds16(src + (size_t)r1 * K + c1, &As[buf][h][g1 * 8]);
  };
  auto stB = [&](int buf, int h, int k0) {
    const u16* src = W + (size_t)(tn + h * 128) * K + k0;
    gl_lds16(src + (size_t)r0 * K + c0, &Bs[buf][h][g0 * 8]);
    gl_lds16(src + (size_t)r1 * K + c1, &Bs[buf][h][g1 * 8]);
  };
  auto ldA = [&](int buf, int h) {
    #pragma unroll
    for (int mi = 0; mi < 4; ++mi)
      #pragma unroll
      for (int ks = 0; ks < 2; ++ks) {
        int row = wm + mi * 16 + lr;
        int c = (ks * 4 + lg) ^ (row & 7);
        af[mi][ks] = *(const bf16x8*)&As[buf][h][row * 64 + c * 8];
      }
  };
  auto ldB = [&](bf16x8 (&bq)[2][2], int buf, int h) {
    #pragma unroll
    for (int ni = 0; ni < 2; ++ni)
      #pragma unroll
      for (int ks = 0; ks < 2; ++ks) {
        int row = wn + ni * 16 + lr;
        int c = (ks * 4 + lg) ^ (row & 7);
        bq[ni][ks] = *(const bf16x8*)&Bs[buf][h][row * 64 + c * 8];
      }
  };

  // prologue: stage tile 0, drain
  stA(0, 0, 0); stB(0, 0, 0); stB(0, 1, 0); stA(0, 1, 0);
  asm volatile("s_waitcnt vmcnt(0)" ::: "memory");
  __syncthreads();

  for (int t = 0; t < 16; ++t) {
    const int cur = t & 1, nxt = cur ^ 1, k1 = (t + 1) * 64;
    const bool st = t < 15;
    // ---- phase 1: quadrant (0,0) ----
    ldA(cur, 0); ldB(bq0, cur, 0);
    if (st) stA(nxt, 0, k1);
    PH_SYNC();
    MMA16(0, 0, bq0);
    if (st) { asm volatile("s_waitcnt vmcnt(4)" ::: "memory"); }
    else    { asm volatile("s_waitcnt vmcnt(2)" ::: "memory"); }
    __builtin_amdgcn_s_barrier();
    // ---- phase 2: quadrant (0,1) ----
    ldB(bq1, cur, 1);
    if (st) stB(nxt, 0, k1);
    PH_SYNC();
    MMA16(0, 1, bq1);
    if (st) { asm volatile("s_waitcnt vmcnt(4)" ::: "memory"); }
    else    { asm volatile("s_waitcnt vmcnt(0)" ::: "memory"); }
    __builtin_amdgcn_s_barrier();
    // ---- phase 3: quadrant (1,1) ----
    ldA(cur, 1);
    if (st) stB(nxt, 1, k1);
    PH_SYNC();
    MMA16(1, 1, bq1);
    __builtin_amdgcn_s_barrier();
    // ---- phase 4: quadrant (1,0) ----
    if (st) stA(nxt, 1, k1);
    PH_SYNC();
    MMA16(1, 0, bq0);
    if (st) { asm volatile("s_waitcnt vmcnt(4)" ::: "memory"); }
    __builtin_amdgcn_s_barrier();
  }

  // epilogue: bias, q-scale, RoPE(q,k), scatter (q linear; k/v frag-major)
  #pragma unroll
  for (int nh = 0; nh < 2; ++nh) {
    #pragma unroll
    for (int ni = 0; ni < 2; ++ni) {
      int n = tn + nh * 128 + wn + ni * 16 + lr;
      float bv = bias[n];
      int sect = n >> 10, nn = n & 1023;
      int h = nn >> 6, d = nn & 63, i2 = d >> 1;
      #pragma unroll
      for (int mh = 0; mh < 2; ++mh) {
        #pragma unroll
        for (int mi = 0; mi < 4; ++mi) {
          #pragma unroll
          for (int r = 0; r < 4; ++r) {
            int m = tm + mh * 128 + wm + mi * 16 + lg * 4 + r;
            int t = m >> 1, bb = m & 1;
            float v = acc[mh][mi][nh][ni][r] + bv;
            if (sect == 0) v *= 0.125f;                 // HD^-0.5
            if (sect < 2) {                             // RoPE (uniform branch)
              float partner = __shfl_xor(v, 1);
              float sp = rel[t * HD_ + i2];
              float cp = rel[t * HD_ + 32 + i2];
              float rot = (d & 1) ? partner : -partner;
              v = v * cp + rot * sp;
            }
            int bh = bb * H_ + h;
            u16 val = f2bf(v);
            if (sect == 0) {
              qb[((size_t)bh * T_ + t) * HD_ + d] = val;
            } else if (sect == 1) {
              int kv = t & 63;
              kp[(((size_t)bh * 32 + (t >> 6)) << 12)
                 + (((kv >> 4) * 2 + (d >> 5)) << 9)
                 + (((d >> 3) & 3) << 7) + ((kv & 15) << 3) + (d & 7)] = val;
            } else {
              int tl = t & 63;
              vp[(((size_t)bh * 32 + (t >> 6)) << 12)
                 + (((tl >> 5) * 4 + (d >> 4)) << 9)
                 + (((tl >> 3) & 3) << 7) + ((d & 15) << 3) + (tl & 7)] = val;
            }
          }
        }
      }
    }
  }
}

// ---------------- Pass D: flash attention ----------------------------------
// grid (T/64, BH); 4 waves, each owns 16 q rows.
// K/V tiles staged to LDS from fragment-major kp/vp (contiguous gl_lds),
// double-buffered; all fragment reads are contiguous ds_read_b128.
__global__ __launch_bounds__(256, 4) void attn_kernel(
    const u16* __restrict__ qbm, const u16* __restrict__ kp,
    const u16* __restrict__ vp, u16* __restrict__ attnb) {
  __shared__ u16 Kl[2][4096];                 // 2 x 8KB
  __shared__ u16 Vl[2][4096];                 // 2 x 8KB
  __shared__ u16 Pl[4][1024];                 // per-wave 2KB, fragment-major
  int orig = blockIdx.y * gridDim.x + blockIdx.x;
  int wgid = xcd_swz(orig, 32 * 32);
  int bh = wgid >> 5;
  int tid = threadIdx.x;
  int w = tid >> 6, lane = tid & 63, lr = lane & 15, lg = lane >> 4;
  int qbase = (wgid & 31) * 64 + w * 16;
  const u16* qrow  = qbm + (size_t)bh * T_ * HD_;
  const u16* ktile = kp + ((size_t)bh * 32) * 4096;
  const u16* vtile = vp + ((size_t)bh * 32) * 4096;
  bf16x8 qf[2];
  #pragma unroll
  for (int ks = 0; ks < 2; ++ks)
    qf[ks] = *(const bf16x8*)&qrow[(size_t)(qbase + lr) * HD_ + ks * 32 + lg * 8];
  const int cb0 = w * 128, cb1 = w * 128 + 64;
  // prologue: stage tile 0 into buf 0
  gl_lds16(ktile + (size_t)(cb0 + lane) * 8, &Kl[0][cb0 * 8]);
  gl_lds16(ktile + (size_t)(cb1 + lane) * 8, &Kl[0][cb1 * 8]);
  gl_lds16(vtile + (size_t)(cb0 + lane) * 8, &Vl[0][cb0 * 8]);
  gl_lds16(vtile + (size_t)(cb1 + lane) * 8, &Vl[0][cb1 * 8]);
  f32x4 o[4] = {};
  float mrun = -INFINITY, lrun = 0.f;
  __syncthreads();
  for (int kt = 0; kt < 32; ++kt) {
    int cur = kt & 1;
    if (kt < 31) {                           // stage next tile into other buf
      const u16* kn = ktile + ((size_t)(kt + 1)) * 4096;
      const u16* vn = vtile + ((size_t)(kt + 1)) * 4096;
      gl_lds16(kn + (size_t)(cb0 + lane) * 8, &Kl[cur ^ 1][cb0 * 8]);
      gl_lds16(kn + (size_t)(cb1 + lane) * 8, &Kl[cur ^ 1][cb1 * 8]);
      gl_lds16(vn + (size_t)(cb0 + lane) * 8, &Vl[cur ^ 1][cb0 * 8]);
      gl_lds16(vn + (size_t)(cb1 + lane) * 8, &Vl[cur ^ 1][cb1 * 8]);
    }
    // QK^T (swapped): St[kv][q]
    f32x4 st[4];
    #pragma unroll
    for (int kb4 = 0; kb4 < 4; ++kb4) {
      st[kb4] = (f32x4){0.f, 0.f, 0.f, 0.f};
      #pragma unroll
      for (int ks = 0; ks < 2; ++ks) {
        bf16x8 a = *(const bf16x8*)&Kl[cur][(kb4 * 2 + ks) * 512 + lane * 8];
        st[kb4] = __builtin_amdgcn_mfma_f32_16x16x32_bf16(a, qf[ks], st[kb4], 0, 0, 0);
      }
    }
    // online softmax (reduce regs then lg groups)
    float mx = -INFINITY;
    #pragma unroll
    for (int kb4 = 0; kb4 < 4; ++kb4)
      #pragma unroll
      for (int r = 0; r < 4; ++r) mx = fmaxf(mx, st[kb4][r]);
    mx = fmaxf(mx, __shfl_xor(mx, 16));
    mx = fmaxf(mx, __shfl_xor(mx, 32));
    if (!__all(mx <= mrun + 8.f)) {          // T13 defer-max rescale
      float mnew = fmaxf(mrun, mx);
      float sc = __expf(mrun - mnew);
      lrun *= sc;
      #pragma unroll
      for (int db = 0; db < 4; ++db) o[db] *= sc;
      mrun = mnew;
    }
    float ls = 0.f;
    #pragma unroll
    for (int kb4 = 0; kb4 < 4; ++kb4) {
      float p0 = __expf(st[kb4][0] - mrun);
      float p1 = __expf(st[kb4][1] - mrun);
      float p2 = __expf(st[kb4][2] - mrun);
      float p3 = __expf(st[kb4][3] - mrun);
      ls += p0 + p1 + p2 + p3;
      uint2 u;
      u.x = (u32)f2bf(p0) | ((u32)f2bf(p1) << 16);
      u.y = (u32)f2bf(p2) | ((u32)f2bf(p3) << 16);
      // fragment-major P: elem (kv,q) at (kv>>3)*128 + q*8 + (kv&7)
      *(uint2*)&Pl[w][((kb4 * 2 + (lg >> 1)) << 7) + (lr << 3) + ((lg & 1) << 2)] = u;
    }
    ls += __shfl_xor(ls, 16);
    ls += __shfl_xor(ls, 32);
    lrun += ls;
    // PV: contiguous pf + vf reads
    #pragma unroll
    for (int ks = 0; ks < 2; ++ks) {
      bf16x8 pf = *(const bf16x8*)&Pl[w][ks * 512 + lane * 8];
      #pragma unroll
      for (int db = 0; db < 4; ++db) {
        bf16x8 vf = *(const bf16x8*)&Vl[cur][(ks * 4 + db) * 512 + lane * 8];
        o[db] = __builtin_amdgcn_mfma_f32_16x16x32_bf16(vf, pf, o[db], 0, 0, 0);
      }
    }
    __syncthreads();                         // drains vmcnt: next tile ready
  }
  float inv = 1.f / lrun;
  int bb = bh >> 4, h = bh & 15;
  int m = (qbase + lr) * 2 + bb;
  #pragma unroll
  for (int db = 0; db < 4; ++db) {
    uint2 u;
    u.x = (u32)f2bf(o[db][0] * inv) | ((u32)f2bf(o[db][1] * inv) << 16);
    u.y = (u32)f2bf(o[db][2] * inv) | ((u32)f2bf(o[db][3] * inv) << 16);
    *(uint2*)&attnb[(size_t)m * E_ + h * 64 + db * 16 + lg * 4] = u;
  }
}

// ---------------- Pass E: out projection GEMM ------------------------------
// out[m][n] = sum_e A[m][e] * W[n][e] + bias[n],  fp32 out
// R5 2-phase dbuf + granule swizzle.
__global__ __launch_bounds__(256) void gemm_out(
    const u16* __restrict__ A, const u16* __restrict__ W,
    const float* __restrict__ bias, float* __restrict__ out) {
  const int K = E_;
  __shared__ u16 As[2][4096];
  __shared__ u16 Bs[2][4096];
  int orig = blockIdx.y * gridDim.x + blockIdx.x;
  int wgid = xcd_swz(orig, 32 * 8);
  const int tm = (wgid & 31) * 128, tn = (wgid >> 5) * 128;
  const int tid = threadIdx.x;
  const int w = tid >> 6, lane = tid & 63, lr = lane & 15, lg = lane >> 4;
  const int wm = (w >> 1) * 64, wn = (w & 1) * 64;
  auto stage = [&](int buf, int k0) {
    #pragma unroll
    for (int hh = 0; hh < 2; ++hh) {
      int ca = (w * 2 + hh) * 64 + lane;
      int ga = ca ^ ((ca >> 3) & 3);
      gl_lds16(A + (size_t)(tm + (ga >> 2)) * K + k0 + (ga & 3) * 8,
               &As[buf][(w * 2 + hh) * 512]);
      gl_lds16(W + (size_t)(tn + (ga >> 2)) * K + k0 + (ga & 3) * 8,
               &Bs[buf][(w * 2 + hh) * 512]);
    }
  };
  f32x4 acc[4][4] = {};
  stage(0, 0);
  __syncthreads();
  for (int it = 0; it < 32; ++it) {
    int cur = it & 1;
    if (it < 31) stage(cur ^ 1, (it + 1) * 32);
    bf16x8 af[4], bq[4];
    #pragma unroll
    for (int mi = 0; mi < 4; ++mi) {
      int ga = (wm + mi * 16 + lr) * 4 + lg; ga ^= (ga >> 3) & 3;
      af[mi] = *(const bf16x8*)&As[cur][ga * 8];
    }
    #pragma unroll
    for (int ni = 0; ni < 4; ++ni) {
      int ga = (wn + ni * 16 + lr) * 4 + lg; ga ^= (ga >> 3) & 3;
      bq[ni] = *(const bf16x8*)&Bs[cur][ga * 8];
    }
    #pragma unroll
    for (int mi = 0; mi < 4; ++mi)
      #pragma unroll
      for (int ni = 0; ni < 4; ++ni)
        acc[mi][ni] = __builtin_amdgcn_mfma_f32_16x16x32_bf16(
            af[mi], bq[ni], acc[mi][ni], 0, 0, 0);
    __syncthreads();
  }
  #pragma unroll
  for (int ni = 0; ni < 4; ++ni) {
    int n = tn + wn + ni * 16 + lr;
    float bv = bias[n];
    #pragma unroll
    for (int mi = 0; mi < 4; ++mi) {
      #pragma unroll
      for (int r = 0; r < 4; ++r) {
        int m = tm + wm + mi * 16 + lg * 4 + r;
        out[(size_t)m * E_ + n] = acc[mi][ni][r] + bv;
      }
    }
  }
}

// ---------------- launch ----------------------------------------------------
extern "C" void kernel_launch(void* const* d_in, const int* in_sizes, int n_in,
                              void* d_out, int out_size, void* d_ws, size_t ws_size,
                              hipStream_t stream) {
  const float* q   = (const float*)d_in[0];
  const float* rel = (const float*)d_in[1];
  const float* wi  = (const float*)d_in[2];
  const float* bi  = (const float*)d_in[3];
  const float* wo  = (const float*)d_in[4];
  const float* bo  = (const float*)d_in[5];
  float* out = (float*)d_out;
  char* ws = (char*)d_ws;
  // ws layout (bytes), 40 MiB total:
  u16* Xb  = (u16*)(ws);                    //  8 MiB  [4096][1024]
  u16* Wib = (u16*)(ws + 8388608);          //  6 MiB  [3072][1024]
  u16* Wob = (u16*)(ws + 14680064);         //  2 MiB  [1024][1024]
  u16* qb  = (u16*)(ws + 16777216);         //  8 MiB  [32][2048][64]
  u16* kpb = (u16*)(ws + 25165824);         //  8 MiB  [32][32][4096] frag-major
  u16* vpb = (u16*)(ws + 33554432);         //  8 MiB  [32][32][4096] frag-major
  u16* attnb = Xb;                          // overlay: X dead after gemm_qkv

  cvt_kernel<<<dim3(8192), dim3(256), 0, stream>>>(q, wi, wo, Xb, Wib, Wob);
  gemm_qkv<<<dim3(192), dim3(512), 0, stream>>>(Xb, Wib, bi, rel, qb, kpb, vpb);
  attn_kernel<<<dim3(32, 32), dim3(256), 0, stream>>>(qb, kpb, vpb, attnb);
  gemm_out<<<dim3(32, 8), dim3(256), 0, stream>>>(attnb, Wob, bo, out);
}

// Round 8
// 147.182 us; speedup vs baseline: 1.1393x; 1.1393x over previous
//
#include <hip/hip_runtime.h>

// Roformer MHA: T=2048 B=2 E=1024 H=16 HD=64
#define T_  2048
#define B_  2
#define E_  1024
#define H_  16
#define HD_ 64
#define M_  4096          // T*B rows
#define N_QKV 3072        // 3*E

typedef unsigned short u16;
typedef unsigned int   u32;
typedef __attribute__((ext_vector_type(8))) __bf16 bf16x8;
typedef __attribute__((ext_vector_type(4))) float  f32x4;

__device__ inline u16 f2bf(float f) {
  u32 u = __float_as_uint(f);
  u += 0x7fffu + ((u >> 16) & 1u);   // RTNE (finite values)
  return (u16)(u >> 16);
}

__device__ inline void gl_lds16(const u16* g, u16* l) {
  __builtin_amdgcn_global_load_lds(
      (const __attribute__((address_space(1))) u32*)g,
      (__attribute__((address_space(3))) u32*)l, 16, 0, 0);
}

// T1: bijective XCD-aware block swizzle (requires nwg % 8 == 0)
__device__ inline int xcd_swz(int orig, int nwg) {
  return (orig & 7) * (nwg >> 3) + (orig >> 3);
}

// ---------------- Pass A: fp32 -> bf16 conversion --------------------------
__global__ __launch_bounds__(256) void cvt_kernel(
    const float* __restrict__ q, const float* __restrict__ wi,
    const float* __restrict__ wo, u16* __restrict__ X,
    u16* __restrict__ Wi, u16* __restrict__ Wo) {
  int idx = blockIdx.x * 256 + threadIdx.x;       // one float4 per thread
  const int n1 = (M_ * E_) / 4, n2 = (3 * E_ * E_) / 4;
  const float4* src; u16* dst; int i;
  if (idx < n1)            { src = (const float4*)q;  dst = X;  i = idx; }
  else if (idx < n1 + n2)  { src = (const float4*)wi; dst = Wi; i = idx - n1; }
  else                     { src = (const float4*)wo; dst = Wo; i = idx - n1 - n2; }
  float4 v = src[i];
  uint2 o;
  o.x = (u32)f2bf(v.x) | ((u32)f2bf(v.y) << 16);
  o.y = (u32)f2bf(v.z) | ((u32)f2bf(v.w) << 16);
  *(uint2*)&dst[(size_t)i * 4] = o;
}

// ---------------- Pass B: QKV GEMM + bias + scale + RoPE -------------------
// C[m][n] = sum_e X[m][e] * W[n][e],  M=4096, N=3072, K=1024
// K-loop: R5 2-phase dbuf + granule XOR-swizzle (0 bank conflicts).
// Epilogue: staged-transpose — build 4x8KB destination images in the dead
// LDS (q row-major / kp,vp frag-major with RoPE applied), then each wave
// dumps one image with 8 fully-coalesced dwordx4 stores. Replaces the
// 64-per-thread scattered u16 stores (the hidden ~40-50 us cost since R2).
__global__ __launch_bounds__(256) void gemm_qkv(
    const u16* __restrict__ X, const u16* __restrict__ W,
    const float* __restrict__ bias, const float* __restrict__ rel,
    u16* __restrict__ qb, u16* __restrict__ kp, u16* __restrict__ vp) {
  const int K = E_;
  __shared__ u16 SH[16384];                         // 32KB: K-loop bufs + epilogue image
  u16 (*As)[4096] = (u16(*)[4096])SH;
  u16 (*Bs)[4096] = (u16(*)[4096])(SH + 8192);
  int orig = blockIdx.y * gridDim.x + blockIdx.x;
  int wgid = xcd_swz(orig, 32 * 24);
  const int tm = (wgid & 31) * 128, tn = (wgid >> 5) * 128;
  const int tid = threadIdx.x;
  const int w = tid >> 6, lane = tid & 63, lr = lane & 15, lg = lane >> 4;
  const int wm = (w >> 1) * 64, wn = (w & 1) * 64;
  auto stage = [&](int buf, int k0) {
    #pragma unroll
    for (int hh = 0; hh < 2; ++hh) {
      int ca = (w * 2 + hh) * 64 + lane;           // linear LDS granule 0..511
      int ga = ca ^ ((ca >> 3) & 3);               // inverse-swizzled source
      gl_lds16(X + (size_t)(tm + (ga >> 2)) * K + k0 + (ga & 3) * 8,
               &As[buf][(w * 2 + hh) * 512]);
      gl_lds16(W + (size_t)(tn + (ga >> 2)) * K + k0 + (ga & 3) * 8,
               &Bs[buf][(w * 2 + hh) * 512]);
    }
  };
  f32x4 acc[4][4] = {};
  stage(0, 0);
  __syncthreads();
  for (int it = 0; it < 32; ++it) {
    int cur = it & 1;
    if (it < 31) stage(cur ^ 1, (it + 1) * 32);
    bf16x8 af[4], bq[4];
    #pragma unroll
    for (int mi = 0; mi < 4; ++mi) {
      int ga = (wm + mi * 16 + lr) * 4 + lg; ga ^= (ga >> 3) & 3;
      af[mi] = *(const bf16x8*)&As[cur][ga * 8];
    }
    #pragma unroll
    for (int ni = 0; ni < 4; ++ni) {
      int ga = (wn + ni * 16 + lr) * 4 + lg; ga ^= (ga >> 3) & 3;
      bq[ni] = *(const bf16x8*)&Bs[cur][ga * 8];
    }
    #pragma unroll
    for (int mi = 0; mi < 4; ++mi)
      #pragma unroll
      for (int ni = 0; ni < 4; ++ni)
        acc[mi][ni] = __builtin_amdgcn_mfma_f32_16x16x32_bf16(
            af[mi], bq[ni], acc[mi][ni], 0, 0, 0);
    __syncthreads();                    // drains stage loads; cur reads done
  }
  // ---- epilogue: build LDS image (4 chunks x 4096 u16), then dump ----
  const int sect = tn >> 10;                        // uniform per block
  #pragma unroll
  for (int ni = 0; ni < 4; ++ni) {
    int n = tn + wn + ni * 16 + lr;
    float bv = bias[n];
    int nn = n & 1023;
    int d = nn & 63, i2 = d >> 1;
    int hsub = (nn >> 6) & 1;
    #pragma unroll
    for (int mi = 0; mi < 4; ++mi) {
      #pragma unroll
      for (int r = 0; r < 4; ++r) {
        int m = tm + wm + mi * 16 + lg * 4 + r;
        int t = m >> 1, bb = m & 1, tl = t & 63;
        float v = acc[mi][ni][r] + bv;
        if (sect == 0) v *= 0.125f;                 // HD^-0.5
        if (sect < 2) {                             // RoPE (uniform branch)
          float partner = __shfl_xor(v, 1);
          float sp = rel[t * HD_ + i2];
          float cp = rel[t * HD_ + 32 + i2];
          float rot = (d & 1) ? partner : -partner;
          v = v * cp + rot * sp;
        }
        int off;
        if (sect == 0)
          off = tl * 64 + d;                        // q: row-major [t][d]
        else if (sect == 1)
          off = (((tl >> 4) * 2 + (d >> 5)) << 9)   // K frag-major
              + (((d >> 3) & 3) << 7) + ((tl & 15) << 3) + (d & 7);
        else
          off = (((tl >> 5) * 4 + (d >> 4)) << 9)   // V^T frag-major
              + (((d >> 3) & 3) << 7) + ((d & 15) << 3) + (tl & 7);
        // NOTE: v-off uses (tl>>3)&3 not (d>>3)&3 — fixed below
        if (sect == 2)
          off = (((tl >> 5) * 4 + (d >> 4)) << 9)
              + (((tl >> 3) & 3) << 7) + ((d & 15) << 3) + (tl & 7);
        SH[((bb << 1) | hsub) * 4096 + off] = f2bf(v);
      }
    }
  }
  __syncthreads();
  {
    // wave w dumps chunk w = (bb<<1)|hsub  ->  bb = w>>1, hsub = w&1
    int h0 = (tn & 1023) >> 6;
    int bb = w >> 1, hs = w & 1;
    int bh = bb * H_ + h0 + hs;
    int t0 = tm >> 1;
    u16* dst;
    if (sect == 0)      dst = qb + ((size_t)bh * T_ + t0) * HD_;
    else if (sect == 1) dst = kp + (((size_t)bh * 32 + (t0 >> 6)) << 12);
    else                dst = vp + (((size_t)bh * 32 + (t0 >> 6)) << 12);
    const u16* srcp = SH + w * 4096;
    #pragma unroll
    for (int i = 0; i < 8; ++i)
      *(uint4*)&dst[(size_t)(i * 64 + lane) * 8] =
          *(const uint4*)&srcp[(i * 64 + lane) * 8];
  }
}

// ---------------- Pass D: flash attention ----------------------------------
// grid (T/64, BH); 4 waves, each owns 16 q rows.
// K/V tiles staged to LDS from fragment-major kp/vp (contiguous gl_lds),
// double-buffered; all fragment reads are contiguous ds_read_b128.
__global__ __launch_bounds__(256, 4) void attn_kernel(
    const u16* __restrict__ qbm, const u16* __restrict__ kp,
    const u16* __restrict__ vp, u16* __restrict__ attnb) {
  __shared__ u16 Kl[2][4096];                 // 2 x 8KB
  __shared__ u16 Vl[2][4096];                 // 2 x 8KB
  __shared__ u16 Pl[4][1024];                 // per-wave 2KB, fragment-major
  int orig = blockIdx.y * gridDim.x + blockIdx.x;
  int wgid = xcd_swz(orig, 32 * 32);
  int bh = wgid >> 5;
  int tid = threadIdx.x;
  int w = tid >> 6, lane = tid & 63, lr = lane & 15, lg = lane >> 4;
  int qbase = (wgid & 31) * 64 + w * 16;
  const u16* qrow  = qbm + (size_t)bh * T_ * HD_;
  const u16* ktile = kp + ((size_t)bh * 32) * 4096;
  const u16* vtile = vp + ((size_t)bh * 32) * 4096;
  bf16x8 qf[2];
  #pragma unroll
  for (int ks = 0; ks < 2; ++ks)
    qf[ks] = *(const bf16x8*)&qrow[(size_t)(qbase + lr) * HD_ + ks * 32 + lg * 8];
  const int cb0 = w * 128, cb1 = w * 128 + 64;
  // prologue: stage tile 0 into buf 0
  gl_lds16(ktile + (size_t)(cb0 + lane) * 8, &Kl[0][cb0 * 8]);
  gl_lds16(ktile + (size_t)(cb1 + lane) * 8, &Kl[0][cb1 * 8]);
  gl_lds16(vtile + (size_t)(cb0 + lane) * 8, &Vl[0][cb0 * 8]);
  gl_lds16(vtile + (size_t)(cb1 + lane) * 8, &Vl[0][cb1 * 8]);
  f32x4 o[4] = {};
  float mrun = -INFINITY, lrun = 0.f;
  __syncthreads();
  for (int kt = 0; kt < 32; ++kt) {
    int cur = kt & 1;
    if (kt < 31) {                           // stage next tile into other buf
      const u16* kn = ktile + ((size_t)(kt + 1)) * 4096;
      const u16* vn = vtile + ((size_t)(kt + 1)) * 4096;
      gl_lds16(kn + (size_t)(cb0 + lane) * 8, &Kl[cur ^ 1][cb0 * 8]);
      gl_lds16(kn + (size_t)(cb1 + lane) * 8, &Kl[cur ^ 1][cb1 * 8]);
      gl_lds16(vn + (size_t)(cb0 + lane) * 8, &Vl[cur ^ 1][cb0 * 8]);
      gl_lds16(vn + (size_t)(cb1 + lane) * 8, &Vl[cur ^ 1][cb1 * 8]);
    }
    // QK^T (swapped): St[kv][q]
    f32x4 st[4];
    #pragma unroll
    for (int kb4 = 0; kb4 < 4; ++kb4) {
      st[kb4] = (f32x4){0.f, 0.f, 0.f, 0.f};
      #pragma unroll
      for (int ks = 0; ks < 2; ++ks) {
        bf16x8 a = *(const bf16x8*)&Kl[cur][(kb4 * 2 + ks) * 512 + lane * 8];
        st[kb4] = __builtin_amdgcn_mfma_f32_16x16x32_bf16(a, qf[ks], st[kb4], 0, 0, 0);
      }
    }
    // online softmax (reduce regs then lg groups)
    float mx = -INFINITY;
    #pragma unroll
    for (int kb4 = 0; kb4 < 4; ++kb4)
      #pragma unroll
      for (int r = 0; r < 4; ++r) mx = fmaxf(mx, st[kb4][r]);
    mx = fmaxf(mx, __shfl_xor(mx, 16));
    mx = fmaxf(mx, __shfl_xor(mx, 32));
    if (!__all(mx <= mrun + 8.f)) {          // T13 defer-max rescale
      float mnew = fmaxf(mrun, mx);
      float sc = __expf(mrun - mnew);
      lrun *= sc;
      #pragma unroll
      for (int db = 0; db < 4; ++db) o[db] *= sc;
      mrun = mnew;
    }
    float ls = 0.f;
    #pragma unroll
    for (int kb4 = 0; kb4 < 4; ++kb4) {
      float p0 = __expf(st[kb4][0] - mrun);
      float p1 = __expf(st[kb4][1] - mrun);
      float p2 = __expf(st[kb4][2] - mrun);
      float p3 = __expf(st[kb4][3] - mrun);
      ls += p0 + p1 + p2 + p3;
      uint2 u;
      u.x = (u32)f2bf(p0) | ((u32)f2bf(p1) << 16);
      u.y = (u32)f2bf(p2) | ((u32)f2bf(p3) << 16);
      // fragment-major P: elem (kv,q) at (kv>>3)*128 + q*8 + (kv&7)
      *(uint2*)&Pl[w][((kb4 * 2 + (lg >> 1)) << 7) + (lr << 3) + ((lg & 1) << 2)] = u;
    }
    ls += __shfl_xor(ls, 16);
    ls += __shfl_xor(ls, 32);
    lrun += ls;
    // PV: contiguous pf + vf reads
    #pragma unroll
    for (int ks = 0; ks < 2; ++ks) {
      bf16x8 pf = *(const bf16x8*)&Pl[w][ks * 512 + lane * 8];
      #pragma unroll
      for (int db = 0; db < 4; ++db) {
        bf16x8 vf = *(const bf16x8*)&Vl[cur][(ks * 4 + db) * 512 + lane * 8];
        o[db] = __builtin_amdgcn_mfma_f32_16x16x32_bf16(vf, pf, o[db], 0, 0, 0);
      }
    }
    __syncthreads();                         // drains vmcnt: next tile ready
  }
  float inv = 1.f / lrun;
  int bb = bh >> 4, h = bh & 15;
  int m = (qbase + lr) * 2 + bb;
  #pragma unroll
  for (int db = 0; db < 4; ++db) {
    uint2 u;
    u.x = (u32)f2bf(o[db][0] * inv) | ((u32)f2bf(o[db][1] * inv) << 16);
    u.y = (u32)f2bf(o[db][2] * inv) | ((u32)f2bf(o[db][3] * inv) << 16);
    *(uint2*)&attnb[(size_t)m * E_ + h * 64 + db * 16 + lg * 4] = u;
  }
}

// ---------------- Pass E: out projection GEMM ------------------------------
// out[m][n] = sum_e A[m][e] * W[n][e] + bias[n],  fp32 out
// R5 2-phase dbuf + granule swizzle.
__global__ __launch_bounds__(256) void gemm_out(
    const u16* __restrict__ A, const u16* __restrict__ W,
    const float* __restrict__ bias, float* __restrict__ out) {
  const int K = E_;
  __shared__ u16 As[2][4096];
  __shared__ u16 Bs[2][4096];
  int orig = blockIdx.y * gridDim.x + blockIdx.x;
  int wgid = xcd_swz(orig, 32 * 8);
  const int tm = (wgid & 31) * 128, tn = (wgid >> 5) * 128;
  const int tid = threadIdx.x;
  const int w = tid >> 6, lane = tid & 63, lr = lane & 15, lg = lane >> 4;
  const int wm = (w >> 1) * 64, wn = (w & 1) * 64;
  auto stage = [&](int buf, int k0) {
    #pragma unroll
    for (int hh = 0; hh < 2; ++hh) {
      int ca = (w * 2 + hh) * 64 + lane;
      int ga = ca ^ ((ca >> 3) & 3);
      gl_lds16(A + (size_t)(tm + (ga >> 2)) * K + k0 + (ga & 3) * 8,
               &As[buf][(w * 2 + hh) * 512]);
      gl_lds16(W + (size_t)(tn + (ga >> 2)) * K + k0 + (ga & 3) * 8,
               &Bs[buf][(w * 2 + hh) * 512]);
    }
  };
  f32x4 acc[4][4] = {};
  stage(0, 0);
  __syncthreads();
  for (int it = 0; it < 32; ++it) {
    int cur = it & 1;
    if (it < 31) stage(cur ^ 1, (it + 1) * 32);
    bf16x8 af[4], bq[4];
    #pragma unroll
    for (int mi = 0; mi < 4; ++mi) {
      int ga = (wm + mi * 16 + lr) * 4 + lg; ga ^= (ga >> 3) & 3;
      af[mi] = *(const bf16x8*)&As[cur][ga * 8];
    }
    #pragma unroll
    for (int ni = 0; ni < 4; ++ni) {
      int ga = (wn + ni * 16 + lr) * 4 + lg; ga ^= (ga >> 3) & 3;
      bq[ni] = *(const bf16x8*)&Bs[cur][ga * 8];
    }
    #pragma unroll
    for (int mi = 0; mi < 4; ++mi)
      #pragma unroll
      for (int ni = 0; ni < 4; ++ni)
        acc[mi][ni] = __builtin_amdgcn_mfma_f32_16x16x32_bf16(
            af[mi], bq[ni], acc[mi][ni], 0, 0, 0);
    __syncthreads();
  }
  #pragma unroll
  for (int ni = 0; ni < 4; ++ni) {
    int n = tn + wn + ni * 16 + lr;
    float bv = bias[n];
    #pragma unroll
    for (int mi = 0; mi < 4; ++mi) {
      #pragma unroll
      for (int r = 0; r < 4; ++r) {
        int m = tm + wm + mi * 16 + lg * 4 + r;
        out[(size_t)m * E_ + n] = acc[mi][ni][r] + bv;
      }
    }
  }
}

// ---------------- launch ----------------------------------------------------
extern "C" void kernel_launch(void* const* d_in, const int* in_sizes, int n_in,
                              void* d_out, int out_size, void* d_ws, size_t ws_size,
                              hipStream_t stream) {
  const float* q   = (const float*)d_in[0];
  const float* rel = (const float*)d_in[1];
  const float* wi  = (const float*)d_in[2];
  const float* bi  = (const float*)d_in[3];
  const float* wo  = (const float*)d_in[4];
  const float* bo  = (const float*)d_in[5];
  float* out = (float*)d_out;
  char* ws = (char*)d_ws;
  // ws layout (bytes), 40 MiB total:
  u16* Xb  = (u16*)(ws);                    //  8 MiB  [4096][1024]
  u16* Wib = (u16*)(ws + 8388608);          //  6 MiB  [3072][1024]
  u16* Wob = (u16*)(ws + 14680064);         //  2 MiB  [1024][1024]
  u16* qb  = (u16*)(ws + 16777216);         //  8 MiB  [32][2048][64]
  u16* kpb = (u16*)(ws + 25165824);         //  8 MiB  [32][32][4096] frag-major
  u16* vpb = (u16*)(ws + 33554432);         //  8 MiB  [32][32][4096] frag-major
  u16* attnb = Xb;                          // overlay: X dead after gemm_qkv

  cvt_kernel<<<dim3(8192), dim3(256), 0, stream>>>(q, wi, wo, Xb, Wib, Wob);
  gemm_qkv<<<dim3(32, 24), dim3(256), 0, stream>>>(Xb, Wib, bi, rel, qb, kpb, vpb);
  attn_kernel<<<dim3(32, 32), dim3(256), 0, stream>>>(qb, kpb, vpb, attnb);
  gemm_out<<<dim3(32, 8), dim3(256), 0, stream>>>(attnb, Wob, bo, out);
}

// Round 9
// 139.619 us; speedup vs baseline: 1.2010x; 1.0542x over previous
//
#include <hip/hip_runtime.h>

// Roformer MHA: T=2048 B=2 E=1024 H=16 HD=64
#define T_  2048
#define B_  2
#define E_  1024
#define H_  16
#define HD_ 64
#define M_  4096          // T*B rows
#define N_QKV 3072        // 3*E

typedef unsigned short u16;
typedef unsigned int   u32;
typedef __attribute__((ext_vector_type(8))) __bf16 bf16x8;
typedef __attribute__((ext_vector_type(4))) float  f32x4;

__device__ inline u16 f2bf(float f) {
  u32 u = __float_as_uint(f);
  u += 0x7fffu + ((u >> 16) & 1u);   // RTNE (finite values)
  return (u16)(u >> 16);
}

__device__ inline u32 cvtpk(float lo, float hi) {   // dst.lo=bf16(lo), dst.hi=bf16(hi)
  u32 r;
  asm("v_cvt_pk_bf16_f32 %0, %1, %2" : "=v"(r) : "v"(lo), "v"(hi));
  return r;
}

__device__ inline void gl_lds16(const u16* g, u16* l) {
  __builtin_amdgcn_global_load_lds(
      (const __attribute__((address_space(1))) u32*)g,
      (__attribute__((address_space(3))) u32*)l, 16, 0, 0);
}

// T1: bijective XCD-aware block swizzle (requires nwg % 8 == 0)
__device__ inline int xcd_swz(int orig, int nwg) {
  return (orig & 7) * (nwg >> 3) + (orig >> 3);
}

// ---------------- Pass A: fp32 -> bf16 conversion --------------------------
__global__ __launch_bounds__(256) void cvt_kernel(
    const float* __restrict__ q, const float* __restrict__ wi,
    const float* __restrict__ wo, u16* __restrict__ X,
    u16* __restrict__ Wi, u16* __restrict__ Wo) {
  int idx = blockIdx.x * 256 + threadIdx.x;       // one float4 per thread
  const int n1 = (M_ * E_) / 4, n2 = (3 * E_ * E_) / 4;
  const float4* src; u16* dst; int i;
  if (idx < n1)            { src = (const float4*)q;  dst = X;  i = idx; }
  else if (idx < n1 + n2)  { src = (const float4*)wi; dst = Wi; i = idx - n1; }
  else                     { src = (const float4*)wo; dst = Wo; i = idx - n1 - n2; }
  float4 v = src[i];
  uint2 o;
  o.x = (u32)f2bf(v.x) | ((u32)f2bf(v.y) << 16);
  o.y = (u32)f2bf(v.z) | ((u32)f2bf(v.w) << 16);
  *(uint2*)&dst[(size_t)i * 4] = o;
}

// ---------------- Pass B: QKV GEMM + bias + scale + RoPE -------------------
// K-loop: 2-phase dbuf + granule XOR-swizzle (0 bank conflicts).
// Epilogue: staged-transpose through dead LDS, coalesced dwordx4 dump.
__global__ __launch_bounds__(256) void gemm_qkv(
    const u16* __restrict__ X, const u16* __restrict__ W,
    const float* __restrict__ bias, const float* __restrict__ rel,
    u16* __restrict__ qb, u16* __restrict__ kp, u16* __restrict__ vp) {
  const int K = E_;
  __shared__ u16 SH[16384];                         // 32KB: K-loop bufs + epilogue image
  u16 (*As)[4096] = (u16(*)[4096])SH;
  u16 (*Bs)[4096] = (u16(*)[4096])(SH + 8192);
  int orig = blockIdx.y * gridDim.x + blockIdx.x;
  int wgid = xcd_swz(orig, 32 * 24);
  const int tm = (wgid & 31) * 128, tn = (wgid >> 5) * 128;
  const int tid = threadIdx.x;
  const int w = tid >> 6, lane = tid & 63, lr = lane & 15, lg = lane >> 4;
  const int wm = (w >> 1) * 64, wn = (w & 1) * 64;
  auto stage = [&](int buf, int k0) {
    #pragma unroll
    for (int hh = 0; hh < 2; ++hh) {
      int ca = (w * 2 + hh) * 64 + lane;           // linear LDS granule 0..511
      int ga = ca ^ ((ca >> 3) & 3);               // inverse-swizzled source
      gl_lds16(X + (size_t)(tm + (ga >> 2)) * K + k0 + (ga & 3) * 8,
               &As[buf][(w * 2 + hh) * 512]);
      gl_lds16(W + (size_t)(tn + (ga >> 2)) * K + k0 + (ga & 3) * 8,
               &Bs[buf][(w * 2 + hh) * 512]);
    }
  };
  f32x4 acc[4][4] = {};
  stage(0, 0);
  __syncthreads();
  for (int it = 0; it < 32; ++it) {
    int cur = it & 1;
    if (it < 31) stage(cur ^ 1, (it + 1) * 32);
    bf16x8 af[4], bq[4];
    #pragma unroll
    for (int mi = 0; mi < 4; ++mi) {
      int ga = (wm + mi * 16 + lr) * 4 + lg; ga ^= (ga >> 3) & 3;
      af[mi] = *(const bf16x8*)&As[cur][ga * 8];
    }
    #pragma unroll
    for (int ni = 0; ni < 4; ++ni) {
      int ga = (wn + ni * 16 + lr) * 4 + lg; ga ^= (ga >> 3) & 3;
      bq[ni] = *(const bf16x8*)&Bs[cur][ga * 8];
    }
    #pragma unroll
    for (int mi = 0; mi < 4; ++mi)
      #pragma unroll
      for (int ni = 0; ni < 4; ++ni)
        acc[mi][ni] = __builtin_amdgcn_mfma_f32_16x16x32_bf16(
            af[mi], bq[ni], acc[mi][ni], 0, 0, 0);
    __syncthreads();                    // drains stage loads; cur reads done
  }
  // ---- epilogue: build LDS image (4 chunks x 4096 u16), then dump ----
  const int sect = tn >> 10;                        // uniform per block
  #pragma unroll
  for (int ni = 0; ni < 4; ++ni) {
    int n = tn + wn + ni * 16 + lr;
    float bv = bias[n];
    int nn = n & 1023;
    int d = nn & 63, i2 = d >> 1;
    int hsub = (nn >> 6) & 1;
    #pragma unroll
    for (int mi = 0; mi < 4; ++mi) {
      #pragma unroll
      for (int r = 0; r < 4; ++r) {
        int m = tm + wm + mi * 16 + lg * 4 + r;
        int t = m >> 1, bb = m & 1, tl = t & 63;
        float v = acc[mi][ni][r] + bv;
        if (sect == 0) v *= 0.125f;                 // HD^-0.5
        if (sect < 2) {                             // RoPE (uniform branch)
          float partner = __shfl_xor(v, 1);
          float sp = rel[t * HD_ + i2];
          float cp = rel[t * HD_ + 32 + i2];
          float rot = (d & 1) ? partner : -partner;
          v = v * cp + rot * sp;
        }
        int off;
        if (sect == 0)
          off = tl * 64 + d;                        // q: row-major [t][d]
        else if (sect == 1)
          off = (((tl >> 4) * 2 + (d >> 5)) << 9)   // K frag-major
              + (((d >> 3) & 3) << 7) + ((tl & 15) << 3) + (d & 7);
        else
          off = (((tl >> 5) * 4 + (d >> 4)) << 9)   // V^T frag-major
              + (((tl >> 3) & 3) << 7) + ((d & 15) << 3) + (tl & 7);
        SH[((bb << 1) | hsub) * 4096 + off] = f2bf(v);
      }
    }
  }
  __syncthreads();
  {
    // wave w dumps chunk w = (bb<<1)|hsub  ->  bb = w>>1, hsub = w&1
    int h0 = (tn & 1023) >> 6;
    int bb = w >> 1, hs = w & 1;
    int bh = bb * H_ + h0 + hs;
    int t0 = tm >> 1;
    u16* dst;
    if (sect == 0)      dst = qb + ((size_t)bh * T_ + t0) * HD_;
    else if (sect == 1) dst = kp + (((size_t)bh * 32 + (t0 >> 6)) << 12);
    else                dst = vp + (((size_t)bh * 32 + (t0 >> 6)) << 12);
    const u16* srcp = SH + w * 4096;
    #pragma unroll
    for (int i = 0; i < 8; ++i)
      *(uint4*)&dst[(size_t)(i * 64 + lane) * 8] =
          *(const uint4*)&srcp[(i * 64 + lane) * 8];
  }
}

// ---------------- Pass D: flash attention ----------------------------------
// grid (T/64, BH); 4 waves, each owns 16 q rows; K/V frag-major staged LDS.
// Softmax P -> PV fragment entirely in-register: cvt_pk_bf16 pairs, then
// permlane32_swap + permlane16_swap redistribute kv across lane groups
// (T12 ported to 16x16 layout). No P LDS round-trip.
__global__ __launch_bounds__(256, 4) void attn_kernel(
    const u16* __restrict__ qbm, const u16* __restrict__ kp,
    const u16* __restrict__ vp, u16* __restrict__ attnb) {
  __shared__ u16 Kl[2][4096];                 // 2 x 8KB
  __shared__ u16 Vl[2][4096];                 // 2 x 8KB
  int orig = blockIdx.y * gridDim.x + blockIdx.x;
  int wgid = xcd_swz(orig, 32 * 32);
  int bh = wgid >> 5;
  int tid = threadIdx.x;
  int w = tid >> 6, lane = tid & 63, lr = lane & 15, lg = lane >> 4;
  int qbase = (wgid & 31) * 64 + w * 16;
  const u16* qrow  = qbm + (size_t)bh * T_ * HD_;
  const u16* ktile = kp + ((size_t)bh * 32) * 4096;
  const u16* vtile = vp + ((size_t)bh * 32) * 4096;
  bf16x8 qf[2];
  #pragma unroll
  for (int ks = 0; ks < 2; ++ks)
    qf[ks] = *(const bf16x8*)&qrow[(size_t)(qbase + lr) * HD_ + ks * 32 + lg * 8];
  const int cb0 = w * 128, cb1 = w * 128 + 64;
  // prologue: stage tile 0 into buf 0
  gl_lds16(ktile + (size_t)(cb0 + lane) * 8, &Kl[0][cb0 * 8]);
  gl_lds16(ktile + (size_t)(cb1 + lane) * 8, &Kl[0][cb1 * 8]);
  gl_lds16(vtile + (size_t)(cb0 + lane) * 8, &Vl[0][cb0 * 8]);
  gl_lds16(vtile + (size_t)(cb1 + lane) * 8, &Vl[0][cb1 * 8]);
  f32x4 o[4] = {};
  float mrun = -INFINITY, lrun = 0.f;
  __syncthreads();
  for (int kt = 0; kt < 32; ++kt) {
    int cur = kt & 1;
    if (kt < 31) {                           // stage next tile into other buf
      const u16* kn = ktile + ((size_t)(kt + 1)) * 4096;
      const u16* vn = vtile + ((size_t)(kt + 1)) * 4096;
      gl_lds16(kn + (size_t)(cb0 + lane) * 8, &Kl[cur ^ 1][cb0 * 8]);
      gl_lds16(kn + (size_t)(cb1 + lane) * 8, &Kl[cur ^ 1][cb1 * 8]);
      gl_lds16(vn + (size_t)(cb0 + lane) * 8, &Vl[cur ^ 1][cb0 * 8]);
      gl_lds16(vn + (size_t)(cb1 + lane) * 8, &Vl[cur ^ 1][cb1 * 8]);
    }
    // QK^T (swapped): st[kb4][r] = S[kv = kb4*16+lg*4+r][q = lr]
    f32x4 st[4];
    #pragma unroll
    for (int kb4 = 0; kb4 < 4; ++kb4) {
      st[kb4] = (f32x4){0.f, 0.f, 0.f, 0.f};
      #pragma unroll
      for (int ks = 0; ks < 2; ++ks) {
        bf16x8 a = *(const bf16x8*)&Kl[cur][(kb4 * 2 + ks) * 512 + lane * 8];
        st[kb4] = __builtin_amdgcn_mfma_f32_16x16x32_bf16(a, qf[ks], st[kb4], 0, 0, 0);
      }
    }
    // online softmax (reduce regs then lg groups)
    float mx = -INFINITY;
    #pragma unroll
    for (int kb4 = 0; kb4 < 4; ++kb4)
      #pragma unroll
      for (int r = 0; r < 4; ++r) mx = fmaxf(mx, st[kb4][r]);
    mx = fmaxf(mx, __shfl_xor(mx, 16));
    mx = fmaxf(mx, __shfl_xor(mx, 32));
    if (!__all(mx <= mrun + 8.f)) {          // T13 defer-max rescale
      float mnew = fmaxf(mrun, mx);
      float sc = __expf(mrun - mnew);
      lrun *= sc;
      #pragma unroll
      for (int db = 0; db < 4; ++db) o[db] *= sc;
      mrun = mnew;
    }
    float ls = 0.f;
    u32 cv[4][2];
    #pragma unroll
    for (int kb4 = 0; kb4 < 4; ++kb4) {
      float p0 = __expf(st[kb4][0] - mrun);
      float p1 = __expf(st[kb4][1] - mrun);
      float p2 = __expf(st[kb4][2] - mrun);
      float p3 = __expf(st[kb4][3] - mrun);
      ls += (p0 + p1) + (p2 + p3);
      cv[kb4][0] = cvtpk(p0, p1);            // lo=r0, hi=r1
      cv[kb4][1] = cvtpk(p2, p3);
    }
    ls += __shfl_xor(ls, 16);
    ls += __shfl_xor(ls, 32);
    lrun += ls;
    // PV: in-register P redistribution (permlane32 + permlane16 swaps).
    // pf32[jj] = cv[ks*2 + (lg>>1)][jj&1] from lane group (lg&1)*2 + (jj>>1)
    #pragma unroll
    for (int ks = 0; ks < 2; ++ks) {
      u32 a = cv[ks * 2][0], b = cv[ks * 2][1];
      u32 c = cv[ks * 2 + 1][0], d = cv[ks * 2 + 1][1];
      asm("v_permlane32_swap_b32 %0, %1" : "+v"(a), "+v"(c)); // a=[A0,A1,C0,C1]
      asm("v_permlane32_swap_b32 %0, %1" : "+v"(b), "+v"(d));
      asm("v_permlane16_swap_b32 %0, %1" : "+v"(a), "+v"(c)); // a=[A0,A2,C0,C2]
      asm("v_permlane16_swap_b32 %0, %1" : "+v"(b), "+v"(d));
      u32 pf32[4] = {a, b, c, d};
      bf16x8 pf = *(const bf16x8*)pf32;
      #pragma unroll
      for (int db = 0; db < 4; ++db) {
        bf16x8 vf = *(const bf16x8*)&Vl[cur][(ks * 4 + db) * 512 + lane * 8];
        o[db] = __builtin_amdgcn_mfma_f32_16x16x32_bf16(vf, pf, o[db], 0, 0, 0);
      }
    }
    __syncthreads();                         // drains vmcnt: next tile ready
  }
  float inv = 1.f / lrun;
  int bb = bh >> 4, h = bh & 15;
  int m = (qbase + lr) * 2 + bb;
  #pragma unroll
  for (int db = 0; db < 4; ++db) {
    uint2 u;
    u.x = cvtpk(o[db][0] * inv, o[db][1] * inv);
    u.y = cvtpk(o[db][2] * inv, o[db][3] * inv);
    *(uint2*)&attnb[(size_t)m * E_ + h * 64 + db * 16 + lg * 4] = u;
  }
}

// ---------------- Pass E: out projection GEMM ------------------------------
// out[m][n] = sum_e A[m][e] * W[n][e] + bias[n],  fp32 out
// 2-phase dbuf + granule swizzle.
__global__ __launch_bounds__(256) void gemm_out(
    const u16* __restrict__ A, const u16* __restrict__ W,
    const float* __restrict__ bias, float* __restrict__ out) {
  const int K = E_;
  __shared__ u16 As[2][4096];
  __shared__ u16 Bs[2][4096];
  int orig = blockIdx.y * gridDim.x + blockIdx.x;
  int wgid = xcd_swz(orig, 32 * 8);
  const int tm = (wgid & 31) * 128, tn = (wgid >> 5) * 128;
  const int tid = threadIdx.x;
  const int w = tid >> 6, lane = tid & 63, lr = lane & 15, lg = lane >> 4;
  const int wm = (w >> 1) * 64, wn = (w & 1) * 64;
  auto stage = [&](int buf, int k0) {
    #pragma unroll
    for (int hh = 0; hh < 2; ++hh) {
      int ca = (w * 2 + hh) * 64 + lane;
      int ga = ca ^ ((ca >> 3) & 3);
      gl_lds16(A + (size_t)(tm + (ga >> 2)) * K + k0 + (ga & 3) * 8,
               &As[buf][(w * 2 + hh) * 512]);
      gl_lds16(W + (size_t)(tn + (ga >> 2)) * K + k0 + (ga & 3) * 8,
               &Bs[buf][(w * 2 + hh) * 512]);
    }
  };
  f32x4 acc[4][4] = {};
  stage(0, 0);
  __syncthreads();
  for (int it = 0; it < 32; ++it) {
    int cur = it & 1;
    if (it < 31) stage(cur ^ 1, (it + 1) * 32);
    bf16x8 af[4], bq[4];
    #pragma unroll
    for (int mi = 0; mi < 4; ++mi) {
      int ga = (wm + mi * 16 + lr) * 4 + lg; ga ^= (ga >> 3) & 3;
      af[mi] = *(const bf16x8*)&As[cur][ga * 8];
    }
    #pragma unroll
    for (int ni = 0; ni < 4; ++ni) {
      int ga = (wn + ni * 16 + lr) * 4 + lg; ga ^= (ga >> 3) & 3;
      bq[ni] = *(const bf16x8*)&Bs[cur][ga * 8];
    }
    #pragma unroll
    for (int mi = 0; mi < 4; ++mi)
      #pragma unroll
      for (int ni = 0; ni < 4; ++ni)
        acc[mi][ni] = __builtin_amdgcn_mfma_f32_16x16x32_bf16(
            af[mi], bq[ni], acc[mi][ni], 0, 0, 0);
    __syncthreads();
  }
  #pragma unroll
  for (int ni = 0; ni < 4; ++ni) {
    int n = tn + wn + ni * 16 + lr;
    float bv = bias[n];
    #pragma unroll
    for (int mi = 0; mi < 4; ++mi) {
      #pragma unroll
      for (int r = 0; r < 4; ++r) {
        int m = tm + wm + mi * 16 + lg * 4 + r;
        out[(size_t)m * E_ + n] = acc[mi][ni][r] + bv;
      }
    }
  }
}

// ---------------- launch ----------------------------------------------------
extern "C" void kernel_launch(void* const* d_in, const int* in_sizes, int n_in,
                              void* d_out, int out_size, void* d_ws, size_t ws_size,
                              hipStream_t stream) {
  const float* q   = (const float*)d_in[0];
  const float* rel = (const float*)d_in[1];
  const float* wi  = (const float*)d_in[2];
  const float* bi  = (const float*)d_in[3];
  const float* wo  = (const float*)d_in[4];
  const float* bo  = (const float*)d_in[5];
  float* out = (float*)d_out;
  char* ws = (char*)d_ws;
  // ws layout (bytes), 40 MiB total:
  u16* Xb  = (u16*)(ws);                    //  8 MiB  [4096][1024]
  u16* Wib = (u16*)(ws + 8388608);          //  6 MiB  [3072][1024]
  u16* Wob = (u16*)(ws + 14680064);         //  2 MiB  [1024][1024]
  u16* qb  = (u16*)(ws + 16777216);         //  8 MiB  [32][2048][64]
  u16* kpb = (u16*)(ws + 25165824);         //  8 MiB  [32][32][4096] frag-major
  u16* vpb = (u16*)(ws + 33554432);         //  8 MiB  [32][32][4096] frag-major
  u16* attnb = Xb;                          // overlay: X dead after gemm_qkv

  cvt_kernel<<<dim3(8192), dim3(256), 0, stream>>>(q, wi, wo, Xb, Wib, Wob);
  gemm_qkv<<<dim3(32, 24), dim3(256), 0, stream>>>(Xb, Wib, bi, rel, qb, kpb, vpb);
  attn_kernel<<<dim3(32, 32), dim3(256), 0, stream>>>(qb, kpb, vpb, attnb);
  gemm_out<<<dim3(32, 8), dim3(256), 0, stream>>>(attnb, Wob, bo, out);
}